// Round 4
// baseline (1206.131 us; speedup 1.0000x reference)
//
#include <hip/hip_runtime.h>
#include <hip/hip_bf16.h>

#define B_N   131072
#define E_N   8
#define D_N   128
#define H_N   128
#define K_N   1024
#define MBLK  16
#define NTHR  256
#define GRID  1024
#define TILES (B_N / MBLK)     // 8192
#define TPB   (TILES / GRID)   // 8 tiles per persistent block

typedef __attribute__((ext_vector_type(8))) short bf16x8;
typedef __attribute__((ext_vector_type(4))) float f32x4;
typedef __attribute__((ext_vector_type(4))) unsigned short u16x4;

__device__ __forceinline__ unsigned short f2bf(float f) {
    union { float f; unsigned int i; } c; c.f = f;
    unsigned int x = c.i;
    return (unsigned short)((x + 0x7fffu + ((x >> 16) & 1u)) >> 16);
}
__device__ __forceinline__ float bf2f(unsigned short u) {
    union { unsigned int i; float f; } c; c.i = ((unsigned int)u) << 16; return c.f;
}

// ---------------------------------------------------------------------------
// Prep: repack gate_w1 [1024][128] f32 -> bf16 MFMA B-fragment order in d_ws.
// ---------------------------------------------------------------------------
__global__ void prep_w1_frags(const float* __restrict__ w1,
                              unsigned short* __restrict__ frag) {
    int t    = blockIdx.x * blockDim.x + threadIdx.x;   // 0..16383
    int lane = t & 63;
    int fgi  = t >> 6;                                  // kstep*8 + nt
    int kst  = fgi >> 3;
    int nt   = fgi & 7;
    int n    = nt * 16 + (lane & 15);
    int k0   = kst * 32 + (lane >> 4) * 8;
    bf16x8 v;
    #pragma unroll
    for (int j = 0; j < 8; ++j)
        v[j] = (short)f2bf(w1[(k0 + j) * H_N + n]);
    *reinterpret_cast<bf16x8*>(frag + (size_t)t * 8) = v;
}

// ---------------------------------------------------------------------------
// Persistent fused MoE kernel: 1024 blocks x 8 tiles, cross-tile pipelined.
// ---------------------------------------------------------------------------
__global__ __launch_bounds__(NTHR, 4)
void moe_fused(const float* __restrict__ feats,
               const unsigned short* __restrict__ w1frag,
               const float* __restrict__ gate_b1,
               const float* __restrict__ ln1_g,
               const float* __restrict__ ln1_b,
               const float* __restrict__ gate_w2,
               const float* __restrict__ gate_b2,
               const float* __restrict__ out_g,
               const float* __restrict__ out_b,
               float* __restrict__ out)
{
    // swizzled bf16 features: element (m,k) at m*1024 + ((k>>3)^(m&7))*8 + (k&7)
    __shared__ __attribute__((aligned(16))) unsigned short featS[MBLK * K_N]; // 32 KB
    __shared__ __attribute__((aligned(16))) unsigned short hSb[MBLK * 136];   // 4.25 KB
    __shared__ float statSumS[MBLK * E_N];   // 0.5 KB
    __shared__ float statSqS [MBLK * E_N];
    __shared__ float muS     [MBLK * E_N];
    __shared__ float srsS    [MBLK * E_N];

    const int tid  = threadIdx.x;
    const int bid  = blockIdx.x;
    const int lane = tid & 63;

    // ---- hoisted per-thread constants
    // phase-1 / phase-4 geometry (i in {0,1}: f = tid + i*256)
    const int m0  = tid >> 5,         dq0 = tid & 31;
    const int m1  = (tid + NTHR) >> 5, dq1 = (tid + NTHR) & 31;
    // out gamma/beta for phase 4 (depend only on dq)
    const f32x4 og0 = *reinterpret_cast<const f32x4*>(out_g + dq0 * 4);
    const f32x4 ob0 = *reinterpret_cast<const f32x4*>(out_b + dq0 * 4);
    const f32x4 og1 = *reinterpret_cast<const f32x4*>(out_g + dq1 * 4);
    const f32x4 ob1 = *reinterpret_cast<const f32x4*>(out_b + dq1 * 4);

    // GEMM geometry
    const int wv   = tid >> 6;       // 0..3
    const int lrow = lane & 15;
    const int lkh  = lane >> 4;
    const int nt0  = wv * 2, nt1 = nt0 + 1;
    const int arow = lrow * K_N;
    const int asw  = lrow & 7;
    const bf16x8* wf = reinterpret_cast<const bf16x8*>(w1frag);

    // payload registers for the in-flight tile
    f32x4 pv0[8], pv1[8];

    // ---- prologue: load tile `bid`
    {
        const size_t base = (size_t)bid * MBLK * D_N;
        #pragma unroll
        for (int e = 0; e < 8; ++e)
            pv0[e] = reinterpret_cast<const f32x4*>(feats + (size_t)e * B_N * D_N + base)[tid];
        #pragma unroll
        for (int e = 0; e < 8; ++e)
            pv1[e] = reinterpret_cast<const f32x4*>(feats + (size_t)e * B_N * D_N + base)[tid + NTHR];
    }

    for (int g = 0; g < TPB; ++g) {
        const size_t b0 = (size_t)(g * GRID + bid) * MBLK;

        __syncthreads();   // featS free (previous tile's phase 4 done)

        // ---- phase 1: payload regs -> bf16 featS (swizzled)
        #pragma unroll
        for (int i = 0; i < 2; ++i) {
            const int m  = i ? m1 : m0;
            const int dq = i ? dq1 : dq0;
            const int sw = m & 7;
            const int mb = m * K_N;
            #pragma unroll
            for (int e = 0; e < 8; ++e) {
                f32x4 v = i ? pv1[e] : pv0[e];
                int k    = e * D_N + dq * 4;
                int uoff = mb + ((((k >> 3) ^ sw) << 3) | (k & 7));
                u16x4 u;
                u[0] = f2bf(v[0]); u[1] = f2bf(v[1]);
                u[2] = f2bf(v[2]); u[3] = f2bf(v[3]);
                *reinterpret_cast<u16x4*>(&featS[uoff]) = u;
            }
        }
        __syncthreads();

        // ---- phase 1.5: per-(m,e) row stats from featS (2 threads per row)
        {
            const int r  = tid >> 1;          // 0..127: m = r>>3, e = r&7
            const int h  = tid & 1;
            const int m  = r >> 3;
            const int e  = r & 7;
            const int sw = m & 7;
            const int mb = m * K_N;
            const int rot = tid & 7;
            float s = 0.f, sq = 0.f;
            #pragma unroll
            for (int q = 0; q < 8; ++q) {
                int k3 = e * 16 + h * 8 + (q ^ rot);
                bf16x8 x8 = *reinterpret_cast<const bf16x8*>(&featS[mb + ((k3 ^ sw) << 3)]);
                #pragma unroll
                for (int j = 0; j < 8; ++j) {
                    float x = bf2f((unsigned short)x8[j]);
                    s += x; sq += x * x;
                }
            }
            s  += __shfl_xor(s, 1);
            sq += __shfl_xor(sq, 1);
            if (h == 0) { statSumS[r] = s; statSqS[r] = sq; }
        }

        // ---- phase 2: GEMM1  h[16][128] = featS @ W1 (MFMA 16x16x32)
        f32x4 acc0 = {0.f, 0.f, 0.f, 0.f};
        f32x4 acc1 = {0.f, 0.f, 0.f, 0.f};
        {
            bf16x8 b0c = wf[((0 * 8 + nt0) << 6) + lane];
            bf16x8 b1c = wf[((0 * 8 + nt1) << 6) + lane];
            #pragma unroll
            for (int kk = 0; kk < 32; ++kk) {
                bf16x8 b0n, b1n;
                if (kk < 31) {
                    b0n = wf[(((kk + 1) * 8 + nt0) << 6) + lane];
                    b1n = wf[(((kk + 1) * 8 + nt1) << 6) + lane];
                }
                bf16x8 a = *reinterpret_cast<const bf16x8*>(
                    &featS[arow + ((((kk << 2) + lkh) ^ asw) << 3)]);
                acc0 = __builtin_amdgcn_mfma_f32_16x16x32_bf16(a, b0c, acc0, 0, 0, 0);
                acc1 = __builtin_amdgcn_mfma_f32_16x16x32_bf16(a, b1c, acc1, 0, 0, 0);
                b0c = b0n; b1c = b1n;
            }
        }

        // ---- issue next tile's payload loads NOW (pv regs are dead).
        // sched_barrier keeps them from hoisting above the K-loop, where their
        // vmcnt would be drained by the B-fragment waits.
        __builtin_amdgcn_sched_barrier(0);
        if (g + 1 < TPB) {
            const size_t basen = ((size_t)(g + 1) * GRID + bid) * MBLK * D_N;
            #pragma unroll
            for (int e = 0; e < 8; ++e)
                pv0[e] = reinterpret_cast<const f32x4*>(feats + (size_t)e * B_N * D_N + basen)[tid];
            #pragma unroll
            for (int e = 0; e < 8; ++e)
                pv1[e] = reinterpret_cast<const f32x4*>(feats + (size_t)e * B_N * D_N + basen)[tid + NTHR];
        }

        // ---- phase 2.5: +bias, exact GELU -> hSb (bf16)
        {
            const int colA = nt0 * 16 + lrow;
            const int colB = nt1 * 16 + lrow;
            const float bA = gate_b1[colA];
            const float bB = gate_b1[colB];
            #pragma unroll
            for (int r = 0; r < 4; ++r) {
                int row  = lkh * 4 + r;
                float vA = acc0[r] + bA;
                float vB = acc1[r] + bB;
                vA = 0.5f * vA * (1.f + erff(vA * 0.70710678118654752f));
                vB = 0.5f * vB * (1.f + erff(vB * 0.70710678118654752f));
                hSb[row * 136 + colA] = f2bf(vA);
                hSb[row * 136 + colB] = f2bf(vB);
            }
        }
        __syncthreads();

        // ---- phase 2.6: LN1 + GEMM2 + softmax -> {mu, srs} per (m,e)
        {
            const int row = tid >> 4;      // sample m
            const int gl  = tid & 15;
            bf16x8 h8 = *reinterpret_cast<const bf16x8*>(&hSb[row * 136 + gl * 8]);
            float hv[8];
            #pragma unroll
            for (int j = 0; j < 8; ++j) hv[j] = bf2f((unsigned short)h8[j]);
            float s = 0.f, sq = 0.f;
            #pragma unroll
            for (int j = 0; j < 8; ++j) { s += hv[j]; sq += hv[j] * hv[j]; }
            #pragma unroll
            for (int msk = 1; msk < 16; msk <<= 1) {
                s  += __shfl_xor(s, msk);
                sq += __shfl_xor(sq, msk);
            }
            float mu  = s * (1.f / 128.f);
            float var = sq * (1.f / 128.f) - mu * mu;
            float rs  = rsqrtf(var + 1e-5f);
            const f32x4* lgv = reinterpret_cast<const f32x4*>(ln1_g + gl * 8);
            const f32x4* lbv = reinterpret_cast<const f32x4*>(ln1_b + gl * 8);
            f32x4 lg0 = lgv[0], lg1 = lgv[1];
            f32x4 lb0 = lbv[0], lb1 = lbv[1];
            float p[8] = {0.f, 0.f, 0.f, 0.f, 0.f, 0.f, 0.f, 0.f};
            #pragma unroll
            for (int j = 0; j < 8; ++j) {
                int col  = gl * 8 + j;
                float gg = (j < 4) ? lg0[j & 3] : lg1[j & 3];
                float bb = (j < 4) ? lb0[j & 3] : lb1[j & 3];
                float hn = (hv[j] - mu) * rs * gg + bb;
                const f32x4* w2v = reinterpret_cast<const f32x4*>(gate_w2 + col * 8);
                f32x4 wa = w2v[0], wb = w2v[1];
                #pragma unroll
                for (int e = 0; e < 4; ++e) p[e]     += hn * wa[e];
                #pragma unroll
                for (int e = 0; e < 4; ++e) p[e + 4] += hn * wb[e];
            }
            #pragma unroll
            for (int msk = 1; msk < 16; msk <<= 1) {
                #pragma unroll
                for (int e = 0; e < 8; ++e) p[e] += __shfl_xor(p[e], msk);
            }
            float lg[8], mx = -3.0e38f;
            #pragma unroll
            for (int e = 0; e < 8; ++e) { lg[e] = p[e] + gate_b2[e]; mx = fmaxf(mx, lg[e]); }
            float den = 0.f, ex[8];
            #pragma unroll
            for (int e = 0; e < 8; ++e) { ex[e] = __expf(lg[e] - mx); den += ex[e]; }
            float inv = 1.f / den;
            if (gl < 8) {
                int r = row * 8 + gl;
                float sc   = ex[gl] * inv;
                float ss   = statSumS[r], qq = statSqS[r];
                float mu2  = ss * (1.f / 128.f);
                float var2 = qq * (1.f / 128.f) - mu2 * mu2;
                float srs  = sc * rsqrtf(sc * sc * var2 + 1e-5f);
                muS[r]  = mu2;
                srsS[r] = srs;
            }
        }
        __syncthreads();

        // ---- phase 4: out = (x - mu) * srs * og + ob, coalesced f32x4 stores
        #pragma unroll
        for (int i = 0; i < 2; ++i) {
            const int m  = i ? m1 : m0;
            const int dq = i ? dq1 : dq0;
            const int sw = m & 7;
            const int mb = m * K_N;
            const f32x4 og = i ? og1 : og0;
            const f32x4 ob = i ? ob1 : ob0;
            #pragma unroll
            for (int e = 0; e < 8; ++e) {
                int k3  = e * 16 + (dq >> 1);
                int off = mb + (((k3 ^ sw) << 3) | ((dq & 1) << 2));
                u16x4 xb = *reinterpret_cast<const u16x4*>(&featS[off]);
                int r = m * 8 + e;
                float mu = muS[r], srs = srsS[r];
                f32x4 o;
                #pragma unroll
                for (int j = 0; j < 4; ++j)
                    o[j] = (bf2f(xb[j]) - mu) * srs * og[j] + ob[j];
                *reinterpret_cast<f32x4*>(out + ((size_t)e * B_N + b0 + m) * D_N + dq * 4) = o;
            }
        }
    }
}

extern "C" void kernel_launch(void* const* d_in, const int* in_sizes, int n_in,
                              void* d_out, int out_size, void* d_ws, size_t ws_size,
                              hipStream_t stream) {
    const float* feats   = (const float*)d_in[0];
    const float* gate_w1 = (const float*)d_in[1];
    const float* gate_b1 = (const float*)d_in[2];
    const float* ln1_g   = (const float*)d_in[3];
    const float* ln1_b   = (const float*)d_in[4];
    const float* gate_w2 = (const float*)d_in[5];
    const float* gate_b2 = (const float*)d_in[6];
    const float* out_g   = (const float*)d_in[7];
    const float* out_b   = (const float*)d_in[8];
    float* outp = (float*)d_out;
    unsigned short* frag = (unsigned short*)d_ws;   // 256 KB bf16 W1 fragments

    prep_w1_frags<<<64, 256, 0, stream>>>(gate_w1, frag);
    moe_fused<<<GRID, NTHR, 0, stream>>>(
        feats, frag, gate_b1, ln1_g, ln1_b, gate_w2, gate_b2, out_g, out_b, outp);
}

// Round 5
// 664.612 us; speedup vs baseline: 1.8148x; 1.8148x over previous
//
#include <hip/hip_runtime.h>
#include <hip/hip_bf16.h>

#define B_N   131072
#define E_N   8
#define D_N   128
#define H_N   128
#define K_N   1024
#define MBLK  16
#define NTHR  1024
#define GRID  1024
#define TPB   ((B_N / MBLK) / GRID)   // 8 tiles per block

typedef __attribute__((ext_vector_type(8))) short bf16x8;
typedef __attribute__((ext_vector_type(4))) float f32x4;
typedef __attribute__((ext_vector_type(8))) unsigned short u16x8;

__device__ __forceinline__ unsigned short f2bf(float f) {
    union { float f; unsigned int i; } c; c.f = f;
    unsigned int x = c.i;
    return (unsigned short)((x + 0x7fffu + ((x >> 16) & 1u)) >> 16);
}
__device__ __forceinline__ float bf2f(unsigned short u) {
    union { unsigned int i; float f; } c; c.i = ((unsigned int)u) << 16; return c.f;
}

// lgkm-only barrier: does NOT drain vmcnt, so global loads/stores stay in
// flight across it (the compiler's __syncthreads would drain vmcnt(0)).
__device__ __forceinline__ void lds_barrier() {
    __builtin_amdgcn_sched_barrier(0);
    asm volatile("s_waitcnt lgkmcnt(0)" ::: "memory");
    __builtin_amdgcn_s_barrier();
    __builtin_amdgcn_sched_barrier(0);
}

// ---------------------------------------------------------------------------
// Prep: repack gate_w1 [1024][128] f32 -> bf16 MFMA B-fragment order in d_ws.
// Frag (kstep, nt): lane l holds B[kstep*32 + (l>>4)*8 + j][nt*16 + (l&15)],
// stored 16B/lane at frag[((kstep*8+nt)*64 + l)*8].
// ---------------------------------------------------------------------------
__global__ void prep_w1_frags(const float* __restrict__ w1,
                              unsigned short* __restrict__ frag) {
    int t    = blockIdx.x * blockDim.x + threadIdx.x;   // 0..16383
    int lane = t & 63;
    int fgi  = t >> 6;
    int kst  = fgi >> 3;
    int nt   = fgi & 7;
    int n    = nt * 16 + (lane & 15);
    int k0   = kst * 32 + (lane >> 4) * 8;
    bf16x8 v;
    #pragma unroll
    for (int j = 0; j < 8; ++j)
        v[j] = (short)f2bf(w1[(k0 + j) * H_N + n]);
    *reinterpret_cast<bf16x8*>(frag + (size_t)t * 8) = v;
}

// ---------------------------------------------------------------------------
// Persistent fused kernel: 1024 threads (16 waves), 1 block/CU, W1 in regs.
// Waves: wv = kg*8 + ng  (kg = k-half of 512, ng = 16-col n-tile).
// Sample mapping for load/stats/score/store phases: m = tid>>6 (wave = sample).
// ---------------------------------------------------------------------------
__global__ __launch_bounds__(NTHR, 4)
void moe_fused(const float* __restrict__ feats,
               const unsigned short* __restrict__ w1frag,
               const float* __restrict__ gate_b1,
               const float* __restrict__ ln1_g,
               const float* __restrict__ ln1_b,
               const float* __restrict__ gate_w2,
               const float* __restrict__ gate_b2,
               const float* __restrict__ out_g,
               const float* __restrict__ out_b,
               float* __restrict__ out)
{
    // swizzled bf16 features, double-buffered: (m,k) at m*1024 + ((k>>3)^(m&7))*8 + (k&7)
    __shared__ __attribute__((aligned(16))) unsigned short featS[2][MBLK * K_N]; // 64 KB
    __shared__ __attribute__((aligned(16))) unsigned short hSb[MBLK * 136];      // 4.25 KB
    __shared__ __attribute__((aligned(16))) float redS[8 * 64 * 4];              // 8 KB
    __shared__ __attribute__((aligned(16))) float w2S[H_N * E_N];                // 4 KB [col][e]
    __shared__ float gb1S[128], l1gS[128], l1bS[128], ogS[128], obS[128], gb2S[8];
    __shared__ float statSum[MBLK * 8], statSq[MBLK * 8], muS[MBLK * 8], srsS[MBLK * 8];

    const int tid  = threadIdx.x;
    const int bid  = blockIdx.x;
    const int lane = tid & 63;
    const int m    = tid >> 6;        // sample index (16 waves = 16 samples)
    const int sub  = tid & 63;
    const int ee   = sub >> 3;        // expert
    const int cc   = sub & 7;         // 16-elem chunk within expert row
    const int sw   = m & 7;

    // GEMM geometry
    const int kg = m >> 3;            // k-half (0/1)
    const int ng = m & 7;             // n-tile
    const int r_ = lane & 15;         // MFMA A-row / D-col
    const int kh = lane >> 4;

    // ---- prologue: params -> LDS (disjoint thread ranges)
    if (tid < 256)       reinterpret_cast<f32x4*>(w2S)[tid] = reinterpret_cast<const f32x4*>(gate_w2)[tid];
    else if (tid < 384)  gb1S[tid - 256] = gate_b1[tid - 256];
    else if (tid < 512)  l1gS[tid - 384] = ln1_g[tid - 384];
    else if (tid < 640)  l1bS[tid - 512] = ln1_b[tid - 512];
    else if (tid < 768)  ogS[tid - 640]  = out_g[tid - 640];
    else if (tid < 896)  obS[tid - 768]  = out_b[tid - 768];
    else if (tid < 904)  gb2S[tid - 896] = gate_b2[tid - 896];

    // ---- prologue: W1 fragments -> registers (64 VGPR/thread, loaded once)
    const bf16x8* wf = reinterpret_cast<const bf16x8*>(w1frag);
    bf16x8 wfr[16];
    #pragma unroll
    for (int i = 0; i < 16; ++i)
        wfr[i] = wf[(((kg * 16 + i) * 8 + ng) << 6) + lane];

    // ---- prologue: payload loads for tile 0 (16 floats/thread)
    f32x4 pv[4];
    {
        const float* base = feats + ((size_t)ee * B_N + (size_t)bid * TPB * MBLK + m) * D_N + cc * 16;
        #pragma unroll
        for (int j = 0; j < 4; ++j) pv[j] = reinterpret_cast<const f32x4*>(base)[j];
    }

    for (int g = 0; g < TPB; ++g) {
        const size_t b0 = (size_t)(bid * TPB + g) * MBLK;
        unsigned short* fS = featS[g & 1];

        // ---- phase 1: cvt payload -> bf16, row stats, swizzled LDS write
        {
            float s = 0.f, sq = 0.f;
            u16x8 ua, ub;
            #pragma unroll
            for (int t2 = 0; t2 < 16; ++t2) {
                float v = pv[t2 >> 2][t2 & 3];
                unsigned short u = f2bf(v);
                float x = bf2f(u);
                s += x; sq += x * x;
                if (t2 < 8) ua[t2] = u; else ub[t2 - 8] = u;
            }
            // stats reduce over the 8 chunks of row (m,ee): tid bits 0..2
            s  += __shfl_xor(s, 1);  sq += __shfl_xor(sq, 1);
            s  += __shfl_xor(s, 2);  sq += __shfl_xor(sq, 2);
            s  += __shfl_xor(s, 4);  sq += __shfl_xor(sq, 4);
            if (cc == 0) { statSum[m * 8 + ee] = s; statSq[m * 8 + ee] = sq; }
            const int kb0 = ee * 16 + cc * 2;
            *reinterpret_cast<u16x8*>(&fS[m * K_N + (((kb0)     ^ sw) << 3)]) = ua;
            *reinterpret_cast<u16x8*>(&fS[m * K_N + (((kb0 + 1) ^ sw) << 3)]) = ub;
        }

        // ---- issue next tile's payload loads (in flight across all barriers)
        if (g + 1 < TPB) {
            const float* basen = feats + ((size_t)ee * B_N + b0 + MBLK + m) * D_N + cc * 16;
            #pragma unroll
            for (int j = 0; j < 4; ++j) pv[j] = reinterpret_cast<const f32x4*>(basen)[j];
        }

        lds_barrier();   // b1: featS + stats visible

        // ---- phase 2: GEMM1 partial (16 MFMA, B operands all in registers)
        f32x4 acc = {0.f, 0.f, 0.f, 0.f};
        {
            const int abase = r_ * K_N;
            #pragma unroll
            for (int i = 0; i < 16; ++i) {
                const int slot = (((kg * 16 + i) << 2) + kh) ^ (r_ & 7);
                bf16x8 a = *reinterpret_cast<const bf16x8*>(&fS[abase + (slot << 3)]);
                acc = __builtin_amdgcn_mfma_f32_16x16x32_bf16(a, wfr[i], acc, 0, 0, 0);
            }
        }
        if (kg == 1)
            *reinterpret_cast<f32x4*>(&redS[(ng * 64 + lane) * 4]) = acc;

        lds_barrier();   // b2: partials visible

        // ---- phase 2.5: k-reduce + bias + exact GELU -> hSb (kg==0 waves)
        if (kg == 0) {
            f32x4 o = *reinterpret_cast<const f32x4*>(&redS[(ng * 64 + lane) * 4]);
            const int col = ng * 16 + r_;
            const float gb = gb1S[col];
            #pragma unroll
            for (int r2 = 0; r2 < 4; ++r2) {
                float v = acc[r2] + o[r2] + gb;
                v = 0.5f * v * (1.f + erff(v * 0.70710678118654752f));
                hSb[(kh * 4 + r2) * 136 + col] = f2bf(v);
            }
        }

        lds_barrier();   // b3: hSb visible

        // ---- phase 2.6: LN1 + GEMM2 + softmax (wave m owns sample m)
        {
            const int c0 = lane * 2;
            unsigned int hh = *reinterpret_cast<const unsigned int*>(&hSb[m * 136 + c0]);
            float h0 = bf2f((unsigned short)(hh & 0xffffu));
            float h1 = bf2f((unsigned short)(hh >> 16));
            float s2 = h0 + h1, q2 = h0 * h0 + h1 * h1;
            #pragma unroll
            for (int msk = 1; msk < 64; msk <<= 1) {
                s2 += __shfl_xor(s2, msk);
                q2 += __shfl_xor(q2, msk);
            }
            float mu  = s2 * (1.f / 128.f);
            float var = q2 * (1.f / 128.f) - mu * mu;
            float rs  = rsqrtf(var + 1e-5f);
            float hn0 = (h0 - mu) * rs * l1gS[c0]     + l1bS[c0];
            float hn1 = (h1 - mu) * rs * l1gS[c0 + 1] + l1bS[c0 + 1];
            f32x4 wa0 = *reinterpret_cast<const f32x4*>(&w2S[c0 * 8]);
            f32x4 wb0 = *reinterpret_cast<const f32x4*>(&w2S[c0 * 8 + 4]);
            f32x4 wa1 = *reinterpret_cast<const f32x4*>(&w2S[(c0 + 1) * 8]);
            f32x4 wb1 = *reinterpret_cast<const f32x4*>(&w2S[(c0 + 1) * 8 + 4]);
            float p[8];
            #pragma unroll
            for (int e = 0; e < 4; ++e) {
                p[e]     = hn0 * wa0[e] + hn1 * wa1[e];
                p[e + 4] = hn0 * wb0[e] + hn1 * wb1[e];
            }
            #pragma unroll
            for (int msk = 1; msk < 64; msk <<= 1) {
                #pragma unroll
                for (int e = 0; e < 8; ++e) p[e] += __shfl_xor(p[e], msk);
            }
            float mx = -3.0e38f;
            #pragma unroll
            for (int e = 0; e < 8; ++e) { p[e] += gb2S[e]; mx = fmaxf(mx, p[e]); }
            float den = 0.f;
            #pragma unroll
            for (int e = 0; e < 8; ++e) { p[e] = __expf(p[e] - mx); den += p[e]; }
            const float inv = 1.f / den;
            if (lane < 8) {
                float pe = p[0];                      // static-index select (no scratch)
                #pragma unroll
                for (int e = 1; e < 8; ++e) pe = (lane == e) ? p[e] : pe;
                float sc   = pe * inv;
                float ss   = statSum[m * 8 + lane], qq = statSq[m * 8 + lane];
                float mu2  = ss * (1.f / 128.f);
                float var2 = qq * (1.f / 128.f) - mu2 * mu2;
                muS[m * 8 + lane]  = mu2;
                srsS[m * 8 + lane] = sc * rsqrtf(sc * sc * var2 + 1e-5f);
            }
        }

        lds_barrier();   // b4: muS/srsS visible

        // ---- phase 4: out = (x - mu)*srs*og + ob   (16 floats/thread)
        {
            const int kb0 = ee * 16 + cc * 2;
            bf16x8 xa = *reinterpret_cast<const bf16x8*>(&fS[m * K_N + (((kb0)     ^ sw) << 3)]);
            bf16x8 xb = *reinterpret_cast<const bf16x8*>(&fS[m * K_N + (((kb0 + 1) ^ sw) << 3)]);
            const float mu  = muS[m * 8 + ee];
            const float srs = srsS[m * 8 + ee];
            float* dst = out + ((size_t)ee * B_N + b0 + m) * D_N + cc * 16;
            const f32x4* ogv = reinterpret_cast<const f32x4*>(&ogS[cc * 16]);
            const f32x4* obv = reinterpret_cast<const f32x4*>(&obS[cc * 16]);
            #pragma unroll
            for (int j = 0; j < 4; ++j) {
                f32x4 og = ogv[j], ob = obv[j];
                f32x4 o;
                #pragma unroll
                for (int q = 0; q < 4; ++q) {
                    int idx = j * 4 + q;
                    unsigned short u = (idx < 8) ? (unsigned short)xa[idx]
                                                 : (unsigned short)xb[idx - 8];
                    o[q] = (bf2f(u) - mu) * srs * og[q] + ob[q];
                }
                reinterpret_cast<f32x4*>(dst)[j] = o;
            }
        }
        // no barrier here: next phase 1 writes the other featS buffer; the
        // next lgkm barrier (b1) orders this phase's LDS reads vs t+2 rewrite.
    }
}

extern "C" void kernel_launch(void* const* d_in, const int* in_sizes, int n_in,
                              void* d_out, int out_size, void* d_ws, size_t ws_size,
                              hipStream_t stream) {
    const float* feats   = (const float*)d_in[0];
    const float* gate_w1 = (const float*)d_in[1];
    const float* gate_b1 = (const float*)d_in[2];
    const float* ln1_g   = (const float*)d_in[3];
    const float* ln1_b   = (const float*)d_in[4];
    const float* gate_w2 = (const float*)d_in[5];
    const float* gate_b2 = (const float*)d_in[6];
    const float* out_g   = (const float*)d_in[7];
    const float* out_b   = (const float*)d_in[8];
    float* outp = (float*)d_out;
    unsigned short* frag = (unsigned short*)d_ws;   // 256 KB bf16 W1 fragments

    prep_w1_frags<<<64, 256, 0, stream>>>(gate_w1, frag);
    moe_fused<<<GRID, NTHR, 0, stream>>>(
        feats, frag, gate_b1, ln1_g, ln1_b, gate_w2, gate_b2, out_g, out_b, outp);
}

// Round 6
// 578.685 us; speedup vs baseline: 2.0843x; 1.1485x over previous
//
#include <hip/hip_runtime.h>
#include <hip/hip_bf16.h>

#define B_N   131072
#define E_N   8
#define D_N   128
#define MBLK  16
#define NTHR  1024
#define GRID  256
#define TPB   ((B_N / MBLK) / GRID)   // 32 tiles per persistent block

typedef __attribute__((ext_vector_type(8))) short bf16x8;
typedef __attribute__((ext_vector_type(4))) float f32x4;

__device__ __forceinline__ unsigned short f2bf(float f) {
    union { float f; unsigned int i; } c; c.f = f;
    unsigned int x = c.i;
    return (unsigned short)((x + 0x7fffu + ((x >> 16) & 1u)) >> 16);
}
__device__ __forceinline__ float bf2f(unsigned short u) {
    union { unsigned int i; float f; } c; c.i = ((unsigned int)u) << 16; return c.f;
}
__device__ __forceinline__ unsigned int cvt_pk_bf16(float lo, float hi) {
    unsigned int r;
    asm("v_cvt_pk_bf16_f32 %0, %1, %2" : "=v"(r) : "v"(lo), "v"(hi));
    return r;
}

// lgkm-only barrier: never drains vmcnt, so DMA loads + output stores stay
// in flight across it.
__device__ __forceinline__ void lds_barrier() {
    __builtin_amdgcn_sched_barrier(0);
    asm volatile("s_waitcnt lgkmcnt(0)" ::: "memory");
    __builtin_amdgcn_s_barrier();
    __builtin_amdgcn_sched_barrier(0);
}

__device__ __forceinline__ void load_lds16(const void* g, void* l) {
    __builtin_amdgcn_global_load_lds(
        (const __attribute__((address_space(1))) void*)g,
        (__attribute__((address_space(3))) void*)l, 16, 0, 0);
}

// ---------------------------------------------------------------------------
// Prep: repack gate_w1 [1024][128] f32 -> bf16 MFMA B-fragment order in d_ws.
// ---------------------------------------------------------------------------
__global__ void prep_w1_frags(const float* __restrict__ w1,
                              unsigned short* __restrict__ frag) {
    int t    = blockIdx.x * blockDim.x + threadIdx.x;   // 0..16383
    int lane = t & 63;
    int fgi  = t >> 6;
    int kst  = fgi >> 3;
    int nt   = fgi & 7;
    int n    = nt * 16 + (lane & 15);
    int k0   = kst * 32 + (lane >> 4) * 8;
    bf16x8 v;
    #pragma unroll
    for (int j = 0; j < 8; ++j)
        v[j] = (short)f2bf(w1[(k0 + j) * D_N + n]);
    *reinterpret_cast<bf16x8*>(frag + (size_t)t * 8) = v;
}

// ---------------------------------------------------------------------------
// Persistent fused kernel: 256 blocks x 1024 thr (16 waves), 1 block/CU.
// Features DMA'd f32 into LDS (source-swizzled), W1 in registers,
// counted-vmcnt cross-tile pipeline, 3 lgkm barriers per tile.
// Swizzle: stored 16B-slot S = s ^ ((s>>3)&7) ^ (m&7)  (within-128B only).
// ---------------------------------------------------------------------------
__global__ __attribute__((amdgpu_flat_work_group_size(NTHR, NTHR),
                          amdgpu_waves_per_eu(4, 4)))
void moe_fused(const float* __restrict__ feats,
               const unsigned short* __restrict__ w1frag,
               const float* __restrict__ gate_b1,
               const float* __restrict__ ln1_g,
               const float* __restrict__ ln1_b,
               const float* __restrict__ gate_w2,
               const float* __restrict__ gate_b2,
               const float* __restrict__ out_g,
               const float* __restrict__ out_b,
               float* __restrict__ out)
{
    __shared__ __attribute__((aligned(16))) float featF[2][MBLK * 1024]; // 128 KB
    __shared__ __attribute__((aligned(16))) float redS[8 * 64 * 4];      // 8 KB
    __shared__ __attribute__((aligned(16))) unsigned short hSb[MBLK * 136]; // 4.25 KB
    __shared__ __attribute__((aligned(16))) float w2S[1024];             // 4 KB
    __shared__ float gb1S[128], l1gS[128], l1bS[128], ogS[128], obS[128], gb2S[8];
    __shared__ float statSum[128], statSq[128], muS[128], srsS[128];

    const int tid = threadIdx.x;
    const int bid = blockIdx.x;
    const int w   = tid >> 6;      // wave id = sample m for A/D/E phases
    const int ln  = tid & 63;
    const int ee  = ln >> 3;       // expert       (phases A, E)
    const int cc  = ln & 7;        // 16-float chunk within expert row

    // GEMM geometry
    const int kg = w >> 3;         // K-half
    const int ng = w & 7;          // n-tile
    const int r_ = ln & 15;        // MFMA A-row / D-col
    const int kh = ln >> 4;        // k-quarter within K=32 step

    // ---- params -> LDS (disjoint ranges)
    if (tid < 256)       reinterpret_cast<f32x4*>(w2S)[tid] = reinterpret_cast<const f32x4*>(gate_w2)[tid];
    else if (tid < 384)  gb1S[tid - 256] = gate_b1[tid - 256];
    else if (tid < 512)  l1gS[tid - 384] = ln1_g[tid - 384];
    else if (tid < 640)  l1bS[tid - 512] = ln1_b[tid - 512];
    else if (tid < 768)  ogS[tid - 640]  = out_g[tid - 640];
    else if (tid < 896)  obS[tid - 768]  = out_b[tid - 768];
    else if (tid < 904)  gb2S[tid - 896] = gate_b2[tid - 896];

    // ---- W1 fragments -> registers (64 VGPR, loaded once per block)
    const bf16x8* wf = reinterpret_cast<const bf16x8*>(w1frag);
    bf16x8 wfr[16];
    #pragma unroll
    for (int i = 0; i < 16; ++i)
        wfr[i] = wf[(((kg * 16 + i) * 8 + ng) << 6) + ln];

    // ---- per-lane DMA global byte offsets (tile-invariant part)
    unsigned dmaOff[4];
    #pragma unroll
    for (int j = 0; j < 4; ++j) {
        int S    = j * 64 + ln;                          // stored slot in row w
        int sl   = S ^ ((S >> 3) & 7) ^ (w & 7);         // logical slot
        int e    = sl >> 5;
        int koff = (sl & 31) * 4;
        dmaOff[j] = (unsigned)(((e * B_N + w) * D_N + koff) * 4);
    }
    // ---- phase A/E LDS byte offsets (within a featF buffer)
    unsigned ldsAoff[4];
    #pragma unroll
    for (int j = 0; j < 4; ++j) {
        int s = ee * 32 + cc * 4 + j;
        int S = s ^ ((s >> 3) & 7) ^ (w & 7);
        ldsAoff[j] = (unsigned)((w * 256 + S) * 16);
    }

    // ---- prologue: DMA tile 0, drain once
    {
        unsigned toff = (unsigned)(bid * TPB) * (MBLK * D_N * 4);
        #pragma unroll
        for (int j = 0; j < 4; ++j)
            load_lds16((const char*)feats + (dmaOff[j] + toff),
                       (char*)&featF[0][0] + w * 4096 + j * 1024);
    }
    asm volatile("s_waitcnt vmcnt(0)" ::: "memory");

    for (int g = 0; g < TPB; ++g) {
        const size_t b0 = (size_t)(bid * TPB + g) * MBLK;
        const float* fS = featF[g & 1];

        lds_barrier();   // DMA(g) complete everywhere; params visible (g=0)

        // ---- issue DMA for tile g+1 into the other buffer
        if (g + 1 < TPB) {
            unsigned toff = (unsigned)(bid * TPB + g + 1) * (MBLK * D_N * 4);
            char* nb = (char*)&featF[(g + 1) & 1][0];
            #pragma unroll
            for (int j = 0; j < 4; ++j)
                load_lds16((const char*)feats + (dmaOff[j] + toff),
                           nb + w * 4096 + j * 1024);
        }

        // ---- phase A: per-(m,e) row stats (f32, conflict-free reads)
        {
            float s = 0.f, q = 0.f;
            #pragma unroll
            for (int j = 0; j < 4; ++j) {
                f32x4 v = *reinterpret_cast<const f32x4*>((const char*)fS + ldsAoff[j]);
                s += v[0] + v[1] + v[2] + v[3];
                q += v[0]*v[0] + v[1]*v[1] + v[2]*v[2] + v[3]*v[3];
            }
            s += __shfl_xor(s, 1); q += __shfl_xor(q, 1);
            s += __shfl_xor(s, 2); q += __shfl_xor(q, 2);
            s += __shfl_xor(s, 4); q += __shfl_xor(q, 4);
            if (cc == 0) { statSum[w * 8 + ee] = s; statSq[w * 8 + ee] = q; }
        }

        // ---- phase B: GEMM1 partial (pack f32->bf16 at read, W1 in regs)
        f32x4 acc = {0.f, 0.f, 0.f, 0.f};
        {
            const int rbase = r_ * 4096;
            const int sw    = r_ & 7;
            #pragma unroll
            for (int i = 0; i < 16; ++i) {
                const int s0 = kg * 128 + i * 8 + kh * 2;
                const int sx = ((kg * 16 + i) & 7) ^ sw;
                f32x4 lo = *reinterpret_cast<const f32x4*>(
                    (const char*)fS + rbase + ((s0 ^ sx) << 4));
                f32x4 hi = *reinterpret_cast<const f32x4*>(
                    (const char*)fS + rbase + (((s0 + 1) ^ sx) << 4));
                union { unsigned int u[4]; bf16x8 v; } a;
                a.u[0] = cvt_pk_bf16(lo[0], lo[1]);
                a.u[1] = cvt_pk_bf16(lo[2], lo[3]);
                a.u[2] = cvt_pk_bf16(hi[0], hi[1]);
                a.u[3] = cvt_pk_bf16(hi[2], hi[3]);
                acc = __builtin_amdgcn_mfma_f32_16x16x32_bf16(a.v, wfr[i], acc, 0, 0, 0);
            }
        }
        if (kg == 1)
            *reinterpret_cast<f32x4*>(&redS[(ng * 64 + ln) * 4]) = acc;

        lds_barrier();   // redS visible

        // ---- phase C: K-reduce + bias + exact GELU -> hSb (kg==0 waves)
        if (kg == 0) {
            f32x4 o = *reinterpret_cast<const f32x4*>(&redS[(ng * 64 + ln) * 4]);
            const int col = ng * 16 + r_;
            const float gb = gb1S[col];
            #pragma unroll
            for (int r2 = 0; r2 < 4; ++r2) {
                float v = acc[r2] + o[r2] + gb;
                v = 0.5f * v * (1.f + erff(v * 0.70710678118654752f));
                hSb[(kh * 4 + r2) * 136 + col] = f2bf(v);
            }
        }

        lds_barrier();   // hSb visible

        // ---- phase D: LN1 + GEMM2 + softmax (wave w owns sample w)
        {
            const int c0 = ln * 2;
            unsigned int hh = *reinterpret_cast<const unsigned int*>(&hSb[w * 136 + c0]);
            float h0 = bf2f((unsigned short)(hh & 0xffffu));
            float h1 = bf2f((unsigned short)(hh >> 16));
            float s2 = h0 + h1, q2 = h0 * h0 + h1 * h1;
            #pragma unroll
            for (int msk = 1; msk < 64; msk <<= 1) {
                s2 += __shfl_xor(s2, msk);
                q2 += __shfl_xor(q2, msk);
            }
            float mu  = s2 * (1.f / 128.f);
            float var = q2 * (1.f / 128.f) - mu * mu;
            float rs  = rsqrtf(var + 1e-5f);
            float hn0 = (h0 - mu) * rs * l1gS[c0]     + l1bS[c0];
            float hn1 = (h1 - mu) * rs * l1gS[c0 + 1] + l1bS[c0 + 1];
            f32x4 wa0 = *reinterpret_cast<const f32x4*>(&w2S[c0 * 8]);
            f32x4 wb0 = *reinterpret_cast<const f32x4*>(&w2S[c0 * 8 + 4]);
            f32x4 wa1 = *reinterpret_cast<const f32x4*>(&w2S[(c0 + 1) * 8]);
            f32x4 wb1 = *reinterpret_cast<const f32x4*>(&w2S[(c0 + 1) * 8 + 4]);
            float p[8];
            #pragma unroll
            for (int e = 0; e < 4; ++e) {
                p[e]     = hn0 * wa0[e] + hn1 * wa1[e];
                p[e + 4] = hn0 * wb0[e] + hn1 * wb1[e];
            }
            #pragma unroll
            for (int msk = 1; msk < 64; msk <<= 1) {
                #pragma unroll
                for (int e = 0; e < 8; ++e) p[e] += __shfl_xor(p[e], msk);
            }
            float mx = -3.0e38f;
            #pragma unroll
            for (int e = 0; e < 8; ++e) { p[e] += gb2S[e]; mx = fmaxf(mx, p[e]); }
            float den = 0.f;
            #pragma unroll
            for (int e = 0; e < 8; ++e) { p[e] = __expf(p[e] - mx); den += p[e]; }
            const float inv = 1.f / den;
            if (ln < 8) {
                float pe = p[0];
                #pragma unroll
                for (int e = 1; e < 8; ++e) pe = (ln == e) ? p[e] : pe;
                float sc   = pe * inv;
                float ss   = statSum[w * 8 + ln], qq = statSq[w * 8 + ln];
                float mu2  = ss * (1.f / 128.f);
                float var2 = qq * (1.f / 128.f) - mu2 * mu2;
                muS[w * 8 + ln]  = mu2;
                srsS[w * 8 + ln] = sc * rsqrtf(sc * sc * var2 + 1e-5f);
            }
        }
        // no barrier: phase E consumes only same-wave LDS writes (muS/srsS)

        // ---- phase E: out = (x - mu)*srs*og + ob  (f32 source, coalesced)
        {
            const float mu  = muS[w * 8 + ee];
            const float srs = srsS[w * 8 + ee];
            float* dst = out + ((size_t)ee * B_N + b0 + w) * D_N + cc * 16;
            const f32x4* ogv = reinterpret_cast<const f32x4*>(&ogS[cc * 16]);
            const f32x4* obv = reinterpret_cast<const f32x4*>(&obS[cc * 16]);
            #pragma unroll
            for (int j = 0; j < 4; ++j) {
                f32x4 x  = *reinterpret_cast<const f32x4*>((const char*)fS + ldsAoff[j]);
                f32x4 og = ogv[j], ob = obv[j];
                f32x4 o;
                #pragma unroll
                for (int q = 0; q < 4; ++q)
                    o[q] = (x[q] - mu) * srs * og[q] + ob[q];
                reinterpret_cast<f32x4*>(dst)[j] = o;
            }
        }

        // wait only the 4 oldest vmem ops (= DMA of g+1); stores stay in flight
        if (g + 1 < TPB)
            asm volatile("s_waitcnt vmcnt(4)" ::: "memory");
    }
}

extern "C" void kernel_launch(void* const* d_in, const int* in_sizes, int n_in,
                              void* d_out, int out_size, void* d_ws, size_t ws_size,
                              hipStream_t stream) {
    const float* feats   = (const float*)d_in[0];
    const float* gate_w1 = (const float*)d_in[1];
    const float* gate_b1 = (const float*)d_in[2];
    const float* ln1_g   = (const float*)d_in[3];
    const float* ln1_b   = (const float*)d_in[4];
    const float* gate_w2 = (const float*)d_in[5];
    const float* gate_b2 = (const float*)d_in[6];
    const float* out_g   = (const float*)d_in[7];
    const float* out_b   = (const float*)d_in[8];
    float* outp = (float*)d_out;
    unsigned short* frag = (unsigned short*)d_ws;   // 256 KB bf16 W1 fragments

    prep_w1_frags<<<64, 256, 0, stream>>>(gate_w1, frag);
    moe_fused<<<GRID, NTHR, 0, stream>>>(
        feats, frag, gate_b1, ln1_g, ln1_b, gate_w2, gate_b2, out_g, out_b, outp);
}

// Round 7
// 554.437 us; speedup vs baseline: 2.1754x; 1.0437x over previous
//
#include <hip/hip_runtime.h>
#include <hip/hip_bf16.h>

#define B_N   131072
#define E_N   8
#define D_N   128
#define MBLK  16
#define NTHR  1024
#define GRID  256
#define TPB   ((B_N / MBLK) / GRID)   // 32 tiles per persistent block

typedef __attribute__((ext_vector_type(8))) short bf16x8;
typedef __attribute__((ext_vector_type(4))) float f32x4;

__device__ __forceinline__ unsigned short f2bf(float f) {
    union { float f; unsigned int i; } c; c.f = f;
    unsigned int x = c.i;
    return (unsigned short)((x + 0x7fffu + ((x >> 16) & 1u)) >> 16);
}
__device__ __forceinline__ float bf2f(unsigned short u) {
    union { unsigned int i; float f; } c; c.i = ((unsigned int)u) << 16; return c.f;
}
__device__ __forceinline__ unsigned int cvt_pk_bf16(float lo, float hi) {
    unsigned int r;
    asm("v_cvt_pk_bf16_f32 %0, %1, %2" : "=v"(r) : "v"(lo), "v"(hi));
    return r;
}

// lgkm-only barrier: never drains vmcnt, so DMA loads + output stores stay
// in flight across it.
__device__ __forceinline__ void lds_barrier() {
    __builtin_amdgcn_sched_barrier(0);
    asm volatile("s_waitcnt lgkmcnt(0)" ::: "memory");
    __builtin_amdgcn_s_barrier();
    __builtin_amdgcn_sched_barrier(0);
}

__device__ __forceinline__ void load_lds16(const void* g, void* l) {
    __builtin_amdgcn_global_load_lds(
        (const __attribute__((address_space(1))) void*)g,
        (__attribute__((address_space(3))) void*)l, 16, 0, 0);
}

// ---------------------------------------------------------------------------
// Prep: repack gate_w1 [1024][128] f32 -> bf16 MFMA B-fragment order in d_ws.
// ---------------------------------------------------------------------------
__global__ void prep_w1_frags(const float* __restrict__ w1,
                              unsigned short* __restrict__ frag) {
    int t    = blockIdx.x * blockDim.x + threadIdx.x;   // 0..16383
    int lane = t & 63;
    int fgi  = t >> 6;
    int kst  = fgi >> 3;
    int nt   = fgi & 7;
    int n    = nt * 16 + (lane & 15);
    int k0   = kst * 32 + (lane >> 4) * 8;
    bf16x8 v;
    #pragma unroll
    for (int j = 0; j < 8; ++j)
        v[j] = (short)f2bf(w1[(k0 + j) * D_N + n]);
    *reinterpret_cast<bf16x8*>(frag + (size_t)t * 8) = v;
}

// ---------------------------------------------------------------------------
// Persistent fused kernel: 256 blocks x 1024 thr (16 waves), 1 block/CU.
// Features DMA'd f32 into LDS (source-swizzled); W1 streamed from L2 with
// depth-2 prefetch (low reg pressure: nothing big lives across phases).
// Counted-vmcnt cross-tile pipeline, 3 lgkm-only barriers per tile.
// Swizzle: stored 16B-slot S = s ^ ((s>>3)&7) ^ (m&7)  (within-128B only).
// ---------------------------------------------------------------------------
__global__ __attribute__((amdgpu_flat_work_group_size(NTHR, NTHR),
                          amdgpu_waves_per_eu(4)))
void moe_fused(const float* __restrict__ feats,
               const unsigned short* __restrict__ w1frag,
               const float* __restrict__ gate_b1,
               const float* __restrict__ ln1_g,
               const float* __restrict__ ln1_b,
               const float* __restrict__ gate_w2,
               const float* __restrict__ gate_b2,
               const float* __restrict__ out_g,
               const float* __restrict__ out_b,
               float* __restrict__ out)
{
    __shared__ __attribute__((aligned(16))) float featF[2][MBLK * 1024]; // 128 KB
    __shared__ __attribute__((aligned(16))) float redS[8 * 64 * 4];      // 8 KB
    __shared__ __attribute__((aligned(16))) unsigned short hSb[MBLK * 136]; // 4.25 KB
    __shared__ __attribute__((aligned(16))) float w2S[1024];             // 4 KB
    __shared__ float gb1S[128], l1gS[128], l1bS[128], ogS[128], obS[128], gb2S[8];
    __shared__ float statSum[128], statSq[128], muS[128], srsS[128];

    const int tid = threadIdx.x;
    const int bid = blockIdx.x;
    const int w   = tid >> 6;      // wave id = sample m for A/D/E phases
    const int ln  = tid & 63;
    const int ee  = ln >> 3;       // expert       (phases A, E)
    const int cc  = ln & 7;        // 16-float chunk within expert row

    // GEMM geometry
    const int kg = w >> 3;         // K-half
    const int ng = w & 7;          // n-tile
    const int r_ = ln & 15;        // MFMA A-row / D-col
    const int kh = ln >> 4;        // k-quarter within K=32 step

    // ---- params -> LDS (disjoint ranges)
    if (tid < 256)       reinterpret_cast<f32x4*>(w2S)[tid] = reinterpret_cast<const f32x4*>(gate_w2)[tid];
    else if (tid < 384)  gb1S[tid - 256] = gate_b1[tid - 256];
    else if (tid < 512)  l1gS[tid - 384] = ln1_g[tid - 384];
    else if (tid < 640)  l1bS[tid - 512] = ln1_b[tid - 512];
    else if (tid < 768)  ogS[tid - 640]  = out_g[tid - 640];
    else if (tid < 896)  obS[tid - 768]  = out_b[tid - 768];
    else if (tid < 904)  gb2S[tid - 896] = gate_b2[tid - 896];

    // ---- W1 fragment stream base for this wave (read from L2 each tile)
    const bf16x8* wf  = reinterpret_cast<const bf16x8*>(w1frag);
    const bf16x8* wfp = wf + (((kg * 16) * 8 + ng) << 6) + ln;  // stride 512/bf16x8 per i

    // ---- per-lane DMA global byte offsets (tile-invariant part)
    unsigned dmaOff[4];
    #pragma unroll
    for (int j = 0; j < 4; ++j) {
        int S    = j * 64 + ln;                          // stored slot in row w
        int sl   = S ^ ((S >> 3) & 7) ^ (w & 7);         // logical slot
        int e    = sl >> 5;
        int koff = (sl & 31) * 4;
        dmaOff[j] = (unsigned)(((e * B_N + w) * D_N + koff) * 4);
    }
    // ---- phase A/E LDS byte offsets (within a featF buffer)
    unsigned ldsAoff[4];
    #pragma unroll
    for (int j = 0; j < 4; ++j) {
        int s = ee * 32 + cc * 4 + j;
        int S = s ^ ((s >> 3) & 7) ^ (w & 7);
        ldsAoff[j] = (unsigned)((w * 256 + S) * 16);
    }

    // ---- prologue: DMA tile 0, drain once
    {
        unsigned toff = (unsigned)(bid * TPB) * (MBLK * D_N * 4);
        #pragma unroll
        for (int j = 0; j < 4; ++j)
            load_lds16((const char*)feats + (dmaOff[j] + toff),
                       (char*)&featF[0][0] + w * 4096 + j * 1024);
    }
    asm volatile("s_waitcnt vmcnt(0)" ::: "memory");

    for (int g = 0; g < TPB; ++g) {
        const size_t b0 = (size_t)(bid * TPB + g) * MBLK;
        const float* fS = featF[g & 1];

        lds_barrier();   // DMA(g) complete everywhere; params visible (g=0)

        // ---- issue DMA for tile g+1 into the other buffer
        if (g + 1 < TPB) {
            unsigned toff = (unsigned)(bid * TPB + g + 1) * (MBLK * D_N * 4);
            char* nb = (char*)&featF[(g + 1) & 1][0];
            #pragma unroll
            for (int j = 0; j < 4; ++j)
                load_lds16((const char*)feats + (dmaOff[j] + toff),
                           nb + w * 4096 + j * 1024);
        }

        // ---- phase A: per-(m,e) row stats (f32, conflict-free reads)
        {
            float s = 0.f, q = 0.f;
            #pragma unroll
            for (int j = 0; j < 4; ++j) {
                f32x4 v = *reinterpret_cast<const f32x4*>((const char*)fS + ldsAoff[j]);
                s += v[0] + v[1] + v[2] + v[3];
                q += v[0]*v[0] + v[1]*v[1] + v[2]*v[2] + v[3]*v[3];
            }
            s += __shfl_xor(s, 1); q += __shfl_xor(q, 1);
            s += __shfl_xor(s, 2); q += __shfl_xor(q, 2);
            s += __shfl_xor(s, 4); q += __shfl_xor(q, 4);
            if (cc == 0) { statSum[w * 8 + ee] = s; statSq[w * 8 + ee] = q; }
        }

        // ---- phase B: GEMM1 partial (W1 streamed from L2, depth-2 prefetch)
        f32x4 acc = {0.f, 0.f, 0.f, 0.f};
        {
            const int rbase = r_ * 4096;
            const int sw    = r_ & 7;
            bf16x8 bc = wfp[0 * 512];
            bf16x8 bn = wfp[1 * 512];
            #pragma unroll
            for (int i = 0; i < 16; ++i) {
                bf16x8 bnn;
                if (i < 14) bnn = wfp[(i + 2) * 512];
                const int s0 = kg * 128 + i * 8 + kh * 2;
                const int sx = ((kg * 16 + i) & 7) ^ sw;
                f32x4 lo = *reinterpret_cast<const f32x4*>(
                    (const char*)fS + rbase + ((s0 ^ sx) << 4));
                f32x4 hi = *reinterpret_cast<const f32x4*>(
                    (const char*)fS + rbase + (((s0 + 1) ^ sx) << 4));
                union { unsigned int u[4]; bf16x8 v; } a;
                a.u[0] = cvt_pk_bf16(lo[0], lo[1]);
                a.u[1] = cvt_pk_bf16(lo[2], lo[3]);
                a.u[2] = cvt_pk_bf16(hi[0], hi[1]);
                a.u[3] = cvt_pk_bf16(hi[2], hi[3]);
                acc = __builtin_amdgcn_mfma_f32_16x16x32_bf16(a.v, bc, acc, 0, 0, 0);
                bc = bn; bn = bnn;
            }
        }
        if (kg == 1)
            *reinterpret_cast<f32x4*>(&redS[(ng * 64 + ln) * 4]) = acc;

        lds_barrier();   // redS visible

        // ---- phase C: K-reduce + bias + exact GELU -> hSb (kg==0 waves)
        if (kg == 0) {
            f32x4 o = *reinterpret_cast<const f32x4*>(&redS[(ng * 64 + ln) * 4]);
            const int col = ng * 16 + r_;
            const float gb = gb1S[col];
            #pragma unroll
            for (int r2 = 0; r2 < 4; ++r2) {
                float v = acc[r2] + o[r2] + gb;
                v = 0.5f * v * (1.f + erff(v * 0.70710678118654752f));
                hSb[(kh * 4 + r2) * 136 + col] = f2bf(v);
            }
        }

        lds_barrier();   // hSb visible

        // ---- phase D: LN1 + GEMM2 + softmax (wave w owns sample w)
        {
            const int c0 = ln * 2;
            unsigned int hh = *reinterpret_cast<const unsigned int*>(&hSb[w * 136 + c0]);
            float h0 = bf2f((unsigned short)(hh & 0xffffu));
            float h1 = bf2f((unsigned short)(hh >> 16));
            float s2 = h0 + h1, q2 = h0 * h0 + h1 * h1;
            #pragma unroll
            for (int msk = 1; msk < 64; msk <<= 1) {
                s2 += __shfl_xor(s2, msk);
                q2 += __shfl_xor(q2, msk);
            }
            float mu  = s2 * (1.f / 128.f);
            float var = q2 * (1.f / 128.f) - mu * mu;
            float rs  = rsqrtf(var + 1e-5f);
            float hn0 = (h0 - mu) * rs * l1gS[c0]     + l1bS[c0];
            float hn1 = (h1 - mu) * rs * l1gS[c0 + 1] + l1bS[c0 + 1];
            f32x4 wa0 = *reinterpret_cast<const f32x4*>(&w2S[c0 * 8]);
            f32x4 wb0 = *reinterpret_cast<const f32x4*>(&w2S[c0 * 8 + 4]);
            f32x4 wa1 = *reinterpret_cast<const f32x4*>(&w2S[(c0 + 1) * 8]);
            f32x4 wb1 = *reinterpret_cast<const f32x4*>(&w2S[(c0 + 1) * 8 + 4]);
            float p[8];
            #pragma unroll
            for (int e = 0; e < 4; ++e) {
                p[e]     = hn0 * wa0[e] + hn1 * wa1[e];
                p[e + 4] = hn0 * wb0[e] + hn1 * wb1[e];
            }
            #pragma unroll
            for (int msk = 1; msk < 64; msk <<= 1) {
                #pragma unroll
                for (int e = 0; e < 8; ++e) p[e] += __shfl_xor(p[e], msk);
            }
            float mx = -3.0e38f;
            #pragma unroll
            for (int e = 0; e < 8; ++e) { p[e] += gb2S[e]; mx = fmaxf(mx, p[e]); }
            float den = 0.f;
            #pragma unroll
            for (int e = 0; e < 8; ++e) { p[e] = __expf(p[e] - mx); den += p[e]; }
            const float inv = 1.f / den;
            if (ln < 8) {
                float pe = p[0];
                #pragma unroll
                for (int e = 1; e < 8; ++e) pe = (ln == e) ? p[e] : pe;
                float sc   = pe * inv;
                float ss   = statSum[w * 8 + ln], qq = statSq[w * 8 + ln];
                float mu2  = ss * (1.f / 128.f);
                float var2 = qq * (1.f / 128.f) - mu2 * mu2;
                muS[w * 8 + ln]  = mu2;
                srsS[w * 8 + ln] = sc * rsqrtf(sc * sc * var2 + 1e-5f);
            }
        }
        // no barrier: phase E consumes only same-wave LDS writes (muS/srsS)

        // ---- phase E: out = (x - mu)*srs*og + ob  (f32 source, coalesced)
        {
            const float mu  = muS[w * 8 + ee];
            const float srs = srsS[w * 8 + ee];
            float* dst = out + ((size_t)ee * B_N + b0 + w) * D_N + cc * 16;
            const f32x4* ogv = reinterpret_cast<const f32x4*>(&ogS[cc * 16]);
            const f32x4* obv = reinterpret_cast<const f32x4*>(&obS[cc * 16]);
            #pragma unroll
            for (int j = 0; j < 4; ++j) {
                f32x4 x  = *reinterpret_cast<const f32x4*>((const char*)fS + ldsAoff[j]);
                f32x4 og = ogv[j], ob = obv[j];
                f32x4 o;
                #pragma unroll
                for (int q = 0; q < 4; ++q)
                    o[q] = (x[q] - mu) * srs * og[q] + ob[q];
                reinterpret_cast<f32x4*>(dst)[j] = o;
            }
        }

        // wait only until 4 vmem ops remain (= this tile's stores); the
        // older DMA(g+1) ops are then complete. Stores are never drained.
        if (g + 1 < TPB)
            asm volatile("s_waitcnt vmcnt(4)" ::: "memory");
    }
}

extern "C" void kernel_launch(void* const* d_in, const int* in_sizes, int n_in,
                              void* d_out, int out_size, void* d_ws, size_t ws_size,
                              hipStream_t stream) {
    const float* feats   = (const float*)d_in[0];
    const float* gate_w1 = (const float*)d_in[1];
    const float* gate_b1 = (const float*)d_in[2];
    const float* ln1_g   = (const float*)d_in[3];
    const float* ln1_b   = (const float*)d_in[4];
    const float* gate_w2 = (const float*)d_in[5];
    const float* gate_b2 = (const float*)d_in[6];
    const float* out_g   = (const float*)d_in[7];
    const float* out_b   = (const float*)d_in[8];
    float* outp = (float*)d_out;
    unsigned short* frag = (unsigned short*)d_ws;   // 256 KB bf16 W1 fragments

    prep_w1_frags<<<64, 256, 0, stream>>>(gate_w1, frag);
    moe_fused<<<GRID, NTHR, 0, stream>>>(
        feats, frag, gate_b1, ln1_g, ln1_b, gate_w2, gate_b2, out_g, out_b, outp);
}

// Round 8
// 396.335 us; speedup vs baseline: 3.0432x; 1.3989x over previous
//
#include <hip/hip_runtime.h>
#include <hip/hip_bf16.h>

#define B_N   131072
#define E_N   8
#define D_N   128
#define MBLK  16
#define NTHR  1024
#define GRID  256
#define TPB   ((B_N / MBLK) / GRID)   // 32 tiles per persistent block

typedef __attribute__((ext_vector_type(8))) short bf16x8;
typedef __attribute__((ext_vector_type(4))) float f32x4;

__device__ __forceinline__ unsigned short f2bf(float f) {
    union { float f; unsigned int i; } c; c.f = f;
    unsigned int x = c.i;
    return (unsigned short)((x + 0x7fffu + ((x >> 16) & 1u)) >> 16);
}
__device__ __forceinline__ float bf2f(unsigned short u) {
    union { unsigned int i; float f; } c; c.i = ((unsigned int)u) << 16; return c.f;
}
__device__ __forceinline__ unsigned int cvt_pk_bf16(float lo, float hi) {
    unsigned int r;
    asm("v_cvt_pk_bf16_f32 %0, %1, %2" : "=v"(r) : "v"(lo), "v"(hi));
    return r;
}

// lgkm-only barrier: never drains vmcnt (DMA + stores stay in flight).
__device__ __forceinline__ void lds_barrier() {
    __builtin_amdgcn_sched_barrier(0);
    asm volatile("s_waitcnt lgkmcnt(0)" ::: "memory");
    __builtin_amdgcn_s_barrier();
    __builtin_amdgcn_sched_barrier(0);
}

__device__ __forceinline__ void load_lds16(const void* g, void* l) {
    __builtin_amdgcn_global_load_lds(
        (const __attribute__((address_space(1))) void*)g,
        (__attribute__((address_space(3))) void*)l, 16, 0, 0);
}

// ---------------------------------------------------------------------------
// Prep: repack gate_w1 [1024][128] f32 -> bf16 MFMA B-fragment order in d_ws.
// ---------------------------------------------------------------------------
__global__ void prep_w1_frags(const float* __restrict__ w1,
                              unsigned short* __restrict__ frag) {
    int t    = blockIdx.x * blockDim.x + threadIdx.x;   // 0..16383
    int lane = t & 63;
    int fgi  = t >> 6;
    int kst  = fgi >> 3;
    int nt   = fgi & 7;
    int n    = nt * 16 + (lane & 15);
    int k0   = kst * 32 + (lane >> 4) * 8;
    bf16x8 v;
    #pragma unroll
    for (int j = 0; j < 8; ++j)
        v[j] = (short)f2bf(w1[(k0 + j) * D_N + n]);
    *reinterpret_cast<bf16x8*>(frag + (size_t)t * 8) = v;
}

// ---------------------------------------------------------------------------
// Persistent fused kernel, R8 ordering:
//   b1 | GEMM(frags streamed first in queue) | issue DMA(g+1) | stats |
//   b2 | GELU-reduce | b3 | LN1+GEMM2+softmax | store | vmcnt(4)
// Frag waits never trap the DMA (DMA is newer in the FIFO); DMA latency
// hides under phases A..E. Phases A/E run in stored-slot order (linear LDS).
// Swizzle (involution): stored S = s ^ ((s>>3)&7) ^ (w&7), within-128B only.
// ---------------------------------------------------------------------------
__global__ __attribute__((amdgpu_flat_work_group_size(NTHR, NTHR),
                          amdgpu_waves_per_eu(4)))
void moe_fused(const float* __restrict__ feats,
               const unsigned short* __restrict__ w1frag,
               const float* __restrict__ gate_b1,
               const float* __restrict__ ln1_g,
               const float* __restrict__ ln1_b,
               const float* __restrict__ gate_w2,
               const float* __restrict__ gate_b2,
               const float* __restrict__ out_g,
               const float* __restrict__ out_b,
               float* __restrict__ out)
{
    __shared__ __attribute__((aligned(16))) float featF[2][MBLK * 1024]; // 128 KB
    __shared__ __attribute__((aligned(16))) float redS[8 * 64 * 4];      // 8 KB
    __shared__ __attribute__((aligned(16))) unsigned short hSb[MBLK * 136];
    __shared__ __attribute__((aligned(16))) float w2tS[E_N * 128];       // [e][col]
    __shared__ float gb1S[128], l1gS[128], l1bS[128], ogS[128], obS[128], gb2S[8];
    __shared__ float statSum[128], statSq[128], muS[128], srsS[128];

    const int tid = threadIdx.x;
    const int bid = blockIdx.x;
    const int w   = tid >> 6;      // wave id = sample m
    const int ln  = tid & 63;

    // GEMM geometry
    const int kg = w >> 3;         // K-half
    const int ng = w & 7;          // n-tile
    const int r_ = ln & 15;        // MFMA A-row / D-col
    const int kh = ln >> 4;        // k-quarter (0..3) within K=32 step

    // ---- params -> LDS (disjoint ranges); w2 transposed to [e][col]
    if (tid < 1024) w2tS[(tid & 7) * 128 + (tid >> 3)] = gate_w2[tid];
    if (tid < 128)       gb1S[tid] = gate_b1[tid];
    else if (tid < 256)  l1gS[tid - 128] = ln1_g[tid - 128];
    else if (tid < 384)  l1bS[tid - 256] = ln1_b[tid - 256];
    else if (tid < 512)  ogS[tid - 384]  = out_g[tid - 384];
    else if (tid < 640)  obS[tid - 512]  = out_b[tid - 512];
    else if (tid < 648)  gb2S[tid - 640] = gate_b2[tid - 640];

    // ---- W1 fragment stream base (L2-resident), stride 512 bf16x8 per kstep
    const bf16x8* wfp = reinterpret_cast<const bf16x8*>(w1frag)
                        + (((kg * 16) * 8 + ng) << 6) + ln;

    // ---- per-lane DMA global byte offsets (tile-invariant part)
    unsigned dmaOff[4];
    #pragma unroll
    for (int j = 0; j < 4; ++j) {
        int S    = j * 64 + ln;                          // stored slot in row w
        int sl   = S ^ ((S >> 3) & 7) ^ (w & 7);         // logical slot
        int e    = sl >> 5;
        int koff = (sl & 31) * 4;
        dmaOff[j] = (unsigned)(((e * B_N + w) * D_N + koff) * 4);
    }

    // ---- prologue: DMA tile 0, drain once
    {
        unsigned toff = (unsigned)(bid * TPB) * (MBLK * D_N * 4);
        #pragma unroll
        for (int j = 0; j < 4; ++j)
            load_lds16((const char*)feats + (dmaOff[j] + toff),
                       (char*)&featF[0][0] + w * 4096 + j * 1024);
    }
    asm volatile("s_waitcnt vmcnt(0)" ::: "memory");

    for (int g = 0; g < TPB; ++g) {
        const size_t b0 = (size_t)(bid * TPB + g) * MBLK;
        const float* fS = featF[g & 1];

        lds_barrier();   // b1: buf[g] DMA'd; prev phase-E LDS reads retired

        // ---- phase B: GEMM1 partial. Frag loads are the OLDEST vmem ops of
        // this tile (issued before the DMA), so their waits trap nothing new.
        f32x4 acc = {0.f, 0.f, 0.f, 0.f};
        {
            const int rbase = r_ * 4096;
            const int sw    = r_ & 7;
            bf16x8 fr0 = wfp[0 * 512];
            bf16x8 fr1 = wfp[1 * 512];
            bf16x8 fr2 = wfp[2 * 512];
            bf16x8 fr3 = wfp[3 * 512];
            #pragma unroll
            for (int i = 0; i < 16; ++i) {
                bf16x8 b = (i & 3) == 0 ? fr0 : (i & 3) == 1 ? fr1
                         : (i & 3) == 2 ? fr2 : fr3;
                const int s0 = kg * 128 + i * 8 + kh * 2;
                const int sx = ((kg * 16 + i) & 7) ^ sw;
                f32x4 lo = *reinterpret_cast<const f32x4*>(
                    (const char*)fS + rbase + ((s0 ^ sx) << 4));
                f32x4 hi = *reinterpret_cast<const f32x4*>(
                    (const char*)fS + rbase + (((s0 + 1) ^ sx) << 4));
                union { unsigned int u[4]; bf16x8 v; } a;
                a.u[0] = cvt_pk_bf16(lo[0], lo[1]);
                a.u[1] = cvt_pk_bf16(lo[2], lo[3]);
                a.u[2] = cvt_pk_bf16(hi[0], hi[1]);
                a.u[3] = cvt_pk_bf16(hi[2], hi[3]);
                acc = __builtin_amdgcn_mfma_f32_16x16x32_bf16(a.v, b, acc, 0, 0, 0);
                if (i < 12) {
                    bf16x8 nf = wfp[(i + 4) * 512];
                    if ((i & 3) == 0) fr0 = nf; else if ((i & 3) == 1) fr1 = nf;
                    else if ((i & 3) == 2) fr2 = nf; else fr3 = nf;
                }
            }
        }
        if (kg == 1)
            *reinterpret_cast<f32x4*>(&redS[(ng * 64 + ln) * 4]) = acc;

        // ---- issue DMA for tile g+1 (newest in FIFO: nothing below waits it)
        if (g + 1 < TPB) {
            unsigned toff = (unsigned)(bid * TPB + g + 1) * (MBLK * D_N * 4);
            char* nb = (char*)&featF[(g + 1) & 1][0];
            #pragma unroll
            for (int j = 0; j < 4; ++j)
                load_lds16((const char*)feats + (dmaOff[j] + toff),
                           nb + w * 4096 + j * 1024);
        }

        // ---- phase A: row stats in stored-slot order (linear, conflict-free)
        // slot j*64+ln has expert e = 2j + (ln>>5)  (XOR swizzle keeps bits>=5)
        {
            #pragma unroll
            for (int j = 0; j < 4; ++j) {
                f32x4 v = *reinterpret_cast<const f32x4*>(
                    (const char*)fS + (unsigned)((w * 256 + j * 64 + ln) * 16));
                float s = v[0] + v[1] + v[2] + v[3];
                float q = v[0]*v[0] + v[1]*v[1] + v[2]*v[2] + v[3]*v[3];
                s += __shfl_xor(s, 1);  q += __shfl_xor(q, 1);
                s += __shfl_xor(s, 2);  q += __shfl_xor(q, 2);
                s += __shfl_xor(s, 4);  q += __shfl_xor(q, 4);
                s += __shfl_xor(s, 8);  q += __shfl_xor(q, 8);
                s += __shfl_xor(s, 16); q += __shfl_xor(q, 16);
                if ((ln & 31) == 0) {
                    int e = 2 * j + (ln >> 5);
                    statSum[w * 8 + e] = s;
                    statSq [w * 8 + e] = q;
                }
            }
        }

        lds_barrier();   // b2: redS visible

        // ---- phase C: K-reduce + bias + exact GELU -> hSb (kg==0 waves)
        if (kg == 0) {
            f32x4 o = *reinterpret_cast<const f32x4*>(&redS[(ng * 64 + ln) * 4]);
            const int col = ng * 16 + r_;
            const float gb = gb1S[col];
            #pragma unroll
            for (int r2 = 0; r2 < 4; ++r2) {
                float v = acc[r2] + o[r2] + gb;
                v = 0.5f * v * (1.f + erff(v * 0.70710678118654752f));
                hSb[(kh * 4 + r2) * 136 + col] = f2bf(v);
            }
        }

        lds_barrier();   // b3: hSb visible

        // ---- phase D: LN1 + GEMM2 + softmax (wave w owns sample w)
        {
            const int c0 = ln * 2;
            unsigned int hh = *reinterpret_cast<const unsigned int*>(&hSb[w * 136 + c0]);
            float h0 = bf2f((unsigned short)(hh & 0xffffu));
            float h1 = bf2f((unsigned short)(hh >> 16));
            float s2 = h0 + h1, q2 = h0 * h0 + h1 * h1;
            #pragma unroll
            for (int msk = 1; msk < 64; msk <<= 1) {
                s2 += __shfl_xor(s2, msk);
                q2 += __shfl_xor(q2, msk);
            }
            float mu  = s2 * (1.f / 128.f);
            float var = q2 * (1.f / 128.f) - mu * mu;
            float rs  = rsqrtf(var + 1e-5f);
            float hn0 = (h0 - mu) * rs * l1gS[c0]     + l1bS[c0];
            float hn1 = (h1 - mu) * rs * l1gS[c0 + 1] + l1bS[c0 + 1];
            float p[8];
            #pragma unroll
            for (int e = 0; e < 8; ++e)
                p[e] = hn0 * w2tS[e * 128 + c0] + hn1 * w2tS[e * 128 + c0 + 1];
            #pragma unroll
            for (int msk = 1; msk < 64; msk <<= 1) {
                #pragma unroll
                for (int e = 0; e < 8; ++e) p[e] += __shfl_xor(p[e], msk);
            }
            float mx = -3.0e38f;
            #pragma unroll
            for (int e = 0; e < 8; ++e) { p[e] += gb2S[e]; mx = fmaxf(mx, p[e]); }
            float den = 0.f;
            #pragma unroll
            for (int e = 0; e < 8; ++e) { p[e] = __expf(p[e] - mx); den += p[e]; }
            const float inv = 1.f / den;
            if (ln < 8) {
                float pe = p[0];
                #pragma unroll
                for (int e = 1; e < 8; ++e) pe = (ln == e) ? p[e] : pe;
                float sc   = pe * inv;
                float ss   = statSum[w * 8 + ln], qq = statSq[w * 8 + ln];
                float mu2  = ss * (1.f / 128.f);
                float var2 = qq * (1.f / 128.f) - mu2 * mu2;
                muS[w * 8 + ln]  = mu2;
                srsS[w * 8 + ln] = sc * rsqrtf(sc * sc * var2 + 1e-5f);
            }
        }
        // (muS/srsS are same-wave RAW; no barrier needed)

        // ---- phase E: output in stored-slot order (linear LDS, coalesced)
        {
            #pragma unroll
            for (int j = 0; j < 4; ++j) {
                int slot = j * 64 + ln;
                int sl   = slot ^ ((slot >> 3) & 7) ^ (w & 7);
                int e    = sl >> 5;
                int k4   = sl & 31;
                f32x4 x = *reinterpret_cast<const f32x4*>(
                    (const char*)fS + (unsigned)((w * 256 + slot) * 16));
                float mu  = muS[w * 8 + e];
                float srs = srsS[w * 8 + e];
                const f32x4 og = *reinterpret_cast<const f32x4*>(&ogS[k4 * 4]);
                const f32x4 ob = *reinterpret_cast<const f32x4*>(&obS[k4 * 4]);
                f32x4 o;
                #pragma unroll
                for (int q = 0; q < 4; ++q)
                    o[q] = (x[q] - mu) * srs * og[q] + ob[q];
                *reinterpret_cast<f32x4*>(
                    out + ((size_t)e * B_N + b0 + w) * D_N + k4 * 4) = o;
            }
        }

        // wait DMA(g+1) complete (leaves only this tile's 4 stores in flight)
        if (g + 1 < TPB)
            asm volatile("s_waitcnt vmcnt(4)" ::: "memory");
    }
}

extern "C" void kernel_launch(void* const* d_in, const int* in_sizes, int n_in,
                              void* d_out, int out_size, void* d_ws, size_t ws_size,
                              hipStream_t stream) {
    const float* feats   = (const float*)d_in[0];
    const float* gate_w1 = (const float*)d_in[1];
    const float* gate_b1 = (const float*)d_in[2];
    const float* ln1_g   = (const float*)d_in[3];
    const float* ln1_b   = (const float*)d_in[4];
    const float* gate_w2 = (const float*)d_in[5];
    const float* gate_b2 = (const float*)d_in[6];
    const float* out_g   = (const float*)d_in[7];
    const float* out_b   = (const float*)d_in[8];
    float* outp = (float*)d_out;
    unsigned short* frag = (unsigned short*)d_ws;   // 256 KB bf16 W1 fragments

    prep_w1_frags<<<64, 256, 0, stream>>>(gate_w1, frag);
    moe_fused<<<GRID, NTHR, 0, stream>>>(
        feats, frag, gate_b1, ln1_g, ln1_b, gate_w2, gate_b2, out_g, out_b, outp);
}